// Round 3
// baseline (39.741 us; speedup 1.0000x reference)
//
#include <hip/hip_runtime.h>
#include <stdint.h>

#define NB    4
#define NL0   2048
#define NL1   2048
#define NC    64
#define KMAX  128
#define CAP   256
#define NG1   9
#define NBINS 729
#define FLOWN (NB*NL0*3)
#define QPB   16
#define TPB   1024

// d_ws layout
#define WS_PAD   64                       // NB*NL1 u8 = 8192 B
#define WS_POS   8256                     // NB*3*NL1 f32 = 98304 B (16B aligned)

// ---- K1: pad dtype detection (flags[0]=int-like, flags[1]=float-like) ----
__global__ __launch_bounds__(256) void detect_kernel(
    const uint32_t* __restrict__ pad, uint32_t* __restrict__ flags)
{
  const int i = blockIdx.x*256 + threadIdx.x;     // 8 blocks -> first 8KB as u32
  const uint32_t v = pad[i];
  int a01 = (v <= 1u);
  int af  = (v == 0u || v == 0x3F800000u);
  a01 = __syncthreads_and(a01);
  af  = __syncthreads_and(af);
  if (threadIdx.x == 0) {
    if (!a01) atomicAnd(&flags[0], 0u);
    if (!af)  atomicAnd(&flags[1], 0u);
  }
}

// ---- K2: decode pad -> u8, transpose pos1 -> SoA [b][3][NL1] ----
__global__ __launch_bounds__(256) void prep_kernel(
    const void* __restrict__ padraw, const float* __restrict__ pos1,
    const uint32_t* __restrict__ flags, uint8_t* __restrict__ padu8,
    float* __restrict__ possoa)
{
  const int g = blockIdx.x*256 + threadIdx.x;     // 32 blocks -> 8192 threads
  const int mode = flags[0] ? 1 : (flags[1] ? 2 : 0);
  uint8_t pv;
  if (mode == 1)      pv = (((const int32_t*)padraw)[g] != 0);
  else if (mode == 2) pv = (((const float*)padraw)[g] != 0.0f);
  else                pv = ((const uint8_t*)padraw)[g];
  padu8[g] = pv;
  #pragma unroll
  for (int k = 0; k < 3; ++k) {
    const int i = g + k*8192;                     // covers NB*NL1*3 = 24576
    const float v = pos1[i];
    const int b = i / 6144;
    const int r = i - b*6144;
    const int j = r / 3;
    const int c = r - j*3;
    possoa[(b*3 + c)*NL1 + j] = v;
  }
}

// ---- K3: main ----
__global__ __launch_bounds__(TPB, 8) void fine_match_kernel(
    const float* __restrict__ x0, const float* __restrict__ x1,
    const float* __restrict__ pos0, const float* __restrict__ possoa,
    const uint8_t* __restrict__ padu8, float* __restrict__ out)
{
  __shared__ float          s_pos[3][NL1];
  __shared__ uint8_t        s_pad[NL1];
  __shared__ float          s_x0[QPB*NC];         // == TPB floats
  __shared__ float          s_p0[QPB][3];
  __shared__ unsigned short s_jj[QPB][CAP];

  const int t = threadIdx.x;
  const int bid = blockIdx.x;
  const int b = bid >> 7;                 // 128 blocks per batch
  const int l0base = (bid & 127) * QPB;

  // ---- staging: all coalesced, single barrier ----
  {
    const float4* src = (const float4*)(possoa + (size_t)b*3*NL1);
    float4* dst = (float4*)(&s_pos[0][0]);
    for (int i = t; i < 3*NL1/4; i += TPB) dst[i] = src[i];
  }
  if (t < NL1/4) ((uint32_t*)s_pad)[t] = ((const uint32_t*)(padu8 + b*NL1))[t];
  s_x0[t] = x0[(size_t)(b*NL0 + l0base)*NC + t];
  if (t < QPB*3) {
    const int q = t/3, c = t - q*3;
    s_p0[q][c] = pos0[(b*NL0 + l0base + q)*3 + c];
  }
  { // zero this block's flow_dist region (drained to L2 by the barrier)
    float4 z4; z4.x = z4.y = z4.z = z4.w = 0.0f;
    float4* bz = (float4*)(out + FLOWN + (size_t)(b*NL0 + l0base)*NBINS);
    for (int i = t; i < QPB*NBINS/4; i += TPB) bz[i] = z4;
  }
  __syncthreads();

  const int wv = t >> 6, lane = t & 63;
  const int l0 = l0base + wv;
  const float p0x = s_p0[wv][0], p0y = s_p0[wv][1], p0z = s_p0[wv][2];

  // ---- phase 1: radius scan + wave compaction (ordered by j) ----
  int cnt = 0;
  #pragma unroll 4
  for (int base = 0; base < NL1; base += 64) {
    const int j = base + lane;
    const float dx = __fsub_rn(s_pos[0][j], p0x);
    const float dy = __fsub_rn(s_pos[1][j], p0y);
    const float dz = __fsub_rn(s_pos[2][j], p0z);
    const float d2 = __fadd_rn(__fadd_rn(__fmul_rn(dx,dx), __fmul_rn(dy,dy)), __fmul_rn(dz,dz));
    const bool ok = d2 < 0.0324f;              // strict <, matches reference
    const uint64_t m = __ballot(ok);
    if (ok) {
      const int pos = cnt + (int)__popcll(m & ((1ull << lane) - 1ull));
      if (pos < CAP) s_jj[wv][pos] = (unsigned short)j;
    }
    cnt += (int)__popcll(m);
  }
  if (cnt > CAP) cnt = CAP;
  __syncthreads();

  // ---- phase 2: pad filter, rare exact rank-select, correlation ----
  const bool over = (cnt > KMAX);
  float corr[4];
  #pragma unroll
  for (int s = 0; s < 4; ++s) corr[s] = -1e30f;
  for (int s = 0; s < 4; ++s) {
    if (64*s >= cnt) break;                    // wave-uniform
    const int i = lane + 64*s;
    if (i < cnt) {
      const int j = (int)s_jj[wv][i];
      bool k = (s_pad[j] == 0);
      if (over && k) {  // rank over ALL in-radius candidates, tie-break by list order
        const float dx = __fsub_rn(s_pos[0][j], p0x);
        const float dy = __fsub_rn(s_pos[1][j], p0y);
        const float dz = __fsub_rn(s_pos[2][j], p0z);
        const float di = __fadd_rn(__fadd_rn(__fmul_rn(dx,dx), __fmul_rn(dy,dy)), __fmul_rn(dz,dz));
        int rank = 0;
        for (int m2 = 0; m2 < cnt; ++m2) {
          const int jm = (int)s_jj[wv][m2];
          const float ex = __fsub_rn(s_pos[0][jm], p0x);
          const float ey = __fsub_rn(s_pos[1][jm], p0y);
          const float ez = __fsub_rn(s_pos[2][jm], p0z);
          const float dm = __fadd_rn(__fadd_rn(__fmul_rn(ex,ex), __fmul_rn(ey,ey)), __fmul_rn(ez,ez));
          rank += (dm < di || (dm == di && m2 < i)) ? 1 : 0;
        }
        if (rank >= KMAX) k = false;
      }
      if (k) {
        const float* xr = x1 + ((size_t)b*NL1 + j)*NC;
        float acc = 0.0f;
        #pragma unroll
        for (int c = 0; c < NC; c += 4) {
          const float4 v = *(const float4*)(xr + c);
          const float4 q = *(const float4*)(&s_x0[wv*NC + c]);
          acc += q.x*v.x + q.y*v.y + q.z*v.z + q.w*v.w;
        }
        corr[s] = acc * 0.125f;   // / sqrt(64)
      }
    }
  }

  // ---- phase 3: wave softmax over kept candidates (corr > -1e30) ----
  float mx = -1e30f;
  #pragma unroll
  for (int s = 0; s < 4; ++s) if (corr[s] > mx) mx = corr[s];
  for (int off = 32; off; off >>= 1) { const float o = __shfl_xor(mx, off); if (o > mx) mx = o; }
  float pr[4]; float sum = 0.0f;
  #pragma unroll
  for (int s = 0; s < 4; ++s) { pr[s] = (corr[s] > -1e30f) ? expf(corr[s] - mx) : 0.0f; sum += pr[s]; }
  for (int off = 32; off; off >>= 1) sum += __shfl_xor(sum, off);
  const float inv = (sum > 0.0f) ? (1.0f / sum) : 0.0f;

  // ---- phase 4: flow + voxel scatter (workgroup-scope atomics into local L2) ----
  float* bins = out + FLOWN + (size_t)((size_t)b*NL0 + l0)*NBINS;
  float fx = 0.0f, fy = 0.0f, fz = 0.0f;
  for (int s = 0; s < 4; ++s) {
    if (64*s >= cnt) break;                    // wave-uniform
    if (pr[s] <= 0.0f) continue;
    const float pv = pr[s] * inv;
    const int j = (int)s_jj[wv][lane + 64*s];
    const float dx = __fsub_rn(s_pos[0][j], p0x);
    const float dy = __fsub_rn(s_pos[1][j], p0y);
    const float dz = __fsub_rn(s_pos[2][j], p0z);
    fx += pv*dx; fy += pv*dy; fz += pv*dz;
    const float cx = __fdiv_rn(__fadd_rn(dx, 0.16f), 0.04f);
    const float cy = __fdiv_rn(__fadd_rn(dy, 0.16f), 0.04f);
    const float cz = __fdiv_rn(__fadd_rn(dz, 0.16f), 0.04f);
    int vx = (int)rintf(cx); vx = vx < 0 ? 0 : (vx > 8 ? 8 : vx);
    int vy = (int)rintf(cy); vy = vy < 0 ? 0 : (vy > 8 ? 8 : vy);
    int vz = (int)rintf(cz); vz = vz < 0 ? 0 : (vz > 8 ? 8 : vz);
    __hip_atomic_fetch_add(&bins[(vx*NG1 + vy)*NG1 + vz], pv,
                           __ATOMIC_RELAXED, __HIP_MEMORY_SCOPE_WORKGROUP);
  }
  for (int off = 32; off; off >>= 1) {
    fx += __shfl_xor(fx, off); fy += __shfl_xor(fy, off); fz += __shfl_xor(fz, off);
  }
  if (lane == 0) {
    float* f = out + (size_t)((size_t)b*NL0 + l0)*3;
    f[0] = fx; f[1] = fy; f[2] = fz;
  }
}

extern "C" void kernel_launch(void* const* d_in, const int* in_sizes, int n_in,
                              void* d_out, int out_size, void* d_ws, size_t ws_size,
                              hipStream_t stream) {
  const float* x0   = (const float*)d_in[0];
  const float* x1   = (const float*)d_in[1];
  const float* pos0 = (const float*)d_in[2];
  const float* pos1 = (const float*)d_in[3];
  const void*  pad  = d_in[4];
  float* out = (float*)d_out;
  (void)in_sizes; (void)n_in; (void)out_size; (void)ws_size;

  uint32_t* flags  = (uint32_t*)d_ws;
  uint8_t*  padu8  = (uint8_t*)d_ws + WS_PAD;
  float*    possoa = (float*)((char*)d_ws + WS_POS);

  hipMemsetAsync(d_ws, 0xFF, 8, stream);
  hipLaunchKernelGGL(detect_kernel, dim3(8), dim3(256), 0, stream,
                     (const uint32_t*)pad, flags);
  hipLaunchKernelGGL(prep_kernel, dim3(32), dim3(256), 0, stream,
                     pad, pos1, flags, padu8, possoa);
  hipLaunchKernelGGL(fine_match_kernel, dim3(NB*NL0/QPB), dim3(TPB), 0, stream,
                     x0, x1, pos0, possoa, padu8, out);
}

// Round 4
// 29.626 us; speedup vs baseline: 1.3415x; 1.3415x over previous
//
#include <hip/hip_runtime.h>
#include <stdint.h>

#define NB    4
#define NL0   2048
#define NL1   2048
#define NC    64
#define KMAX  128
#define CAP   256
#define NG1   9
#define NBINS 729
#define FLOWN (NB*NL0*3)
#define QPB   8
#define TPB   512

__global__ __launch_bounds__(TPB, 8) void fine_match_kernel(
    const float* __restrict__ x0, const float* __restrict__ x1,
    const float* __restrict__ pos0, const float* __restrict__ pos1,
    const void* __restrict__ padraw, float* __restrict__ out)
{
  __shared__ float          s_pos[NL1*3];     // AoS: stride-3 word reads are bank-conflict-free (gcd(3,32)=1)
  __shared__ float          s_x0[QPB*NC];
  __shared__ float          s_p0[QPB][3];
  __shared__ unsigned short s_jj[QPB][CAP];
  __shared__ float          s_corr[QPB][CAP]; // lane-private slots; register relief, no extra barrier

  const int t = threadIdx.x;
  const int bid = blockIdx.x;
  const int b = bid >> 8;                 // 256 blocks per batch
  const int l0base = (bid & 255) * QPB;

  // ---- pad width detection: 4-byte (i32/f32 bool) vs packed byte ----
  int wide;
  {
    const uint32_t* pi = (const uint32_t*)padraw;
    int ok4 = 1;
    for (int i = t; i < (NB*NL1)/4; i += TPB) {
      const uint32_t v = pi[i];
      ok4 &= (int)((v <= 1u) | (v == 0x3F800000u));
    }
    wide = __syncthreads_and(ok4);        // block-uniform
  }

  // ---- staging: raw float4 copy of pos1 (AoS), x0 rows, pos0; zero flow_dist ----
  {
    const float4* src = (const float4*)(pos1 + (size_t)b*NL1*3);
    float4* dst = (float4*)s_pos;
    for (int i = t; i < NL1*3/4; i += TPB) dst[i] = src[i];   // 3 per thread
  }
  s_x0[t] = x0[(size_t)(b*NL0 + l0base)*NC + t];              // TPB == QPB*NC
  if (t < QPB*3) {
    const int q = t/3, c = t - q*3;
    s_p0[q][c] = pos0[(b*NL0 + l0base + q)*3 + c];
  }
  {
    float4 z4; z4.x = z4.y = z4.z = z4.w = 0.0f;
    float4* bz = (float4*)(out + FLOWN + (size_t)(b*NL0 + l0base)*NBINS);
    for (int i = t; i < QPB*NBINS/4; i += TPB) bz[i] = z4;    // 1458 float4s
  }
  __syncthreads();   // also drains zero-stores before any atomics

  const int wv = t >> 6, lane = t & 63;
  const int l0 = l0base + wv;
  const float p0x = s_p0[wv][0], p0y = s_p0[wv][1], p0z = s_p0[wv][2];

  // ---- phase 1: radius scan + wave compaction (ordered by j) ----
  int cnt = 0;
  for (int base = 0; base < NL1; base += 64) {
    const int j = base + lane;
    const float dx = __fsub_rn(s_pos[j*3+0], p0x);
    const float dy = __fsub_rn(s_pos[j*3+1], p0y);
    const float dz = __fsub_rn(s_pos[j*3+2], p0z);
    const float d2 = __fadd_rn(__fadd_rn(__fmul_rn(dx,dx), __fmul_rn(dy,dy)), __fmul_rn(dz,dz));
    const bool ok = d2 < 0.0324f;              // strict <, matches reference
    const uint64_t m = __ballot(ok);
    if (ok) {
      const int pos = cnt + (int)__popcll(m & ((1ull << lane) - 1ull));
      if (pos < CAP) s_jj[wv][pos] = (unsigned short)j;
    }
    cnt += (int)__popcll(m);
  }
  if (cnt > CAP) cnt = CAP;
  __syncthreads();

  // ---- phase 2: pad filter, rare exact rank-select, correlation ----
  const bool over = (cnt > KMAX);
  for (int s = 0; s < 4; ++s) {
    if (64*s >= cnt) break;                    // wave-uniform early exit
    const int i = lane + 64*s;
    if (i < cnt) {
      float c = -1e30f;
      const int j = (int)s_jj[wv][i];
      bool k;
      if (wide) k = (((const uint32_t*)padraw)[b*NL1 + j] == 0u);   // i32 and f32(+0/1.0) identical
      else      k = (((const uint8_t*)padraw)[b*NL1 + j] == 0);
      if (over && k) {  // rank over ALL in-radius candidates, tie-break by list order
        const float dx = __fsub_rn(s_pos[j*3+0], p0x);
        const float dy = __fsub_rn(s_pos[j*3+1], p0y);
        const float dz = __fsub_rn(s_pos[j*3+2], p0z);
        const float di = __fadd_rn(__fadd_rn(__fmul_rn(dx,dx), __fmul_rn(dy,dy)), __fmul_rn(dz,dz));
        int rank = 0;
        for (int m2 = 0; m2 < cnt; ++m2) {
          const int jm = (int)s_jj[wv][m2];
          const float ex = __fsub_rn(s_pos[jm*3+0], p0x);
          const float ey = __fsub_rn(s_pos[jm*3+1], p0y);
          const float ez = __fsub_rn(s_pos[jm*3+2], p0z);
          const float dm = __fadd_rn(__fadd_rn(__fmul_rn(ex,ex), __fmul_rn(ey,ey)), __fmul_rn(ez,ez));
          rank += (dm < di || (dm == di && m2 < i)) ? 1 : 0;
        }
        if (rank >= KMAX) k = false;
      }
      if (k) {
        const float* xr = x1 + ((size_t)b*NL1 + j)*NC;
        float acc = 0.0f;
        #pragma unroll
        for (int cc = 0; cc < NC; cc += 4) {
          const float4 v = *(const float4*)(xr + cc);
          const float4 q = *(const float4*)(&s_x0[wv*NC + cc]);  // same addr all lanes: broadcast
          acc += q.x*v.x + q.y*v.y + q.z*v.z + q.w*v.w;
        }
        c = acc * 0.125f;   // / sqrt(64)
      }
      s_corr[wv][i] = c;
    }
  }

  // ---- phase 3: wave softmax stats (max, sum) ----
  float mx = -1e30f;
  for (int s = 0; s < 4; ++s) {
    if (64*s >= cnt) break;
    const int i = lane + 64*s;
    if (i < cnt) { const float c = s_corr[wv][i]; if (c > mx) mx = c; }
  }
  for (int off = 32; off; off >>= 1) { const float o = __shfl_xor(mx, off); if (o > mx) mx = o; }
  float sum = 0.0f;
  for (int s = 0; s < 4; ++s) {
    if (64*s >= cnt) break;
    const int i = lane + 64*s;
    if (i < cnt) { const float c = s_corr[wv][i]; if (c > -1e30f) sum += expf(c - mx); }
  }
  for (int off = 32; off; off >>= 1) sum += __shfl_xor(sum, off);
  const float inv = (sum > 0.0f) ? (1.0f / sum) : 0.0f;

  // ---- phase 4: flow + voxel scatter (workgroup-scope atomics into local L2) ----
  float* bins = out + FLOWN + (size_t)((size_t)b*NL0 + l0)*NBINS;
  float fx = 0.0f, fy = 0.0f, fz = 0.0f;
  for (int s = 0; s < 4; ++s) {
    if (64*s >= cnt) break;
    const int i = lane + 64*s;
    if (i < cnt) {
      const float c = s_corr[wv][i];
      if (c > -1e30f) {
        const float pv = expf(c - mx) * inv;     // bit-identical to phase-3 term * inv
        const int j = (int)s_jj[wv][i];
        const float dx = __fsub_rn(s_pos[j*3+0], p0x);
        const float dy = __fsub_rn(s_pos[j*3+1], p0y);
        const float dz = __fsub_rn(s_pos[j*3+2], p0z);
        fx += pv*dx; fy += pv*dy; fz += pv*dz;
        const float cx = __fdiv_rn(__fadd_rn(dx, 0.16f), 0.04f);
        const float cy = __fdiv_rn(__fadd_rn(dy, 0.16f), 0.04f);
        const float cz = __fdiv_rn(__fadd_rn(dz, 0.16f), 0.04f);
        int vx = (int)rintf(cx); vx = vx < 0 ? 0 : (vx > 8 ? 8 : vx);
        int vy = (int)rintf(cy); vy = vy < 0 ? 0 : (vy > 8 ? 8 : vy);
        int vz = (int)rintf(cz); vz = vz < 0 ? 0 : (vz > 8 ? 8 : vz);
        __hip_atomic_fetch_add(&bins[(vx*NG1 + vy)*NG1 + vz], pv,
                               __ATOMIC_RELAXED, __HIP_MEMORY_SCOPE_WORKGROUP);
      }
    }
  }
  for (int off = 32; off; off >>= 1) {
    fx += __shfl_xor(fx, off); fy += __shfl_xor(fy, off); fz += __shfl_xor(fz, off);
  }
  if (lane == 0) {
    float* f = out + (size_t)((size_t)b*NL0 + l0)*3;
    f[0] = fx; f[1] = fy; f[2] = fz;
  }
}

extern "C" void kernel_launch(void* const* d_in, const int* in_sizes, int n_in,
                              void* d_out, int out_size, void* d_ws, size_t ws_size,
                              hipStream_t stream) {
  const float* x0   = (const float*)d_in[0];
  const float* x1   = (const float*)d_in[1];
  const float* pos0 = (const float*)d_in[2];
  const float* pos1 = (const float*)d_in[3];
  const void*  pad  = d_in[4];
  float* out = (float*)d_out;
  (void)in_sizes; (void)n_in; (void)out_size; (void)d_ws; (void)ws_size;
  hipLaunchKernelGGL(fine_match_kernel, dim3(NB*NL0/QPB), dim3(TPB), 0, stream,
                     x0, x1, pos0, pos1, pad, out);
}